// Round 1
// baseline (211.091 us; speedup 1.0000x reference)
//
#include <hip/hip_runtime.h>
#include <hip/hip_bf16.h>
#include <math.h>

#define B_ 8
#define L_ 4096
#define C_ 512
#define LO_ 2048   // L/2
#define SLOTS 8
#define LM_ 2056   // SLOTS + LO_

__device__ __forceinline__ float waveReduceSum(float v){
  #pragma unroll
  for (int off = 32; off; off >>= 1) v += __shfl_xor(v, off);
  return v;
}

// ---------------- LN1 + carrier score (fused, wave per row) ----------------
__global__ __launch_bounds__(256) void k_scores(
    const float* __restrict__ lat, const float* __restrict__ g1, const float* __restrict__ b1,
    const float* __restrict__ cw, const float* __restrict__ cbp, float* __restrict__ scores)
{
  int row  = blockIdx.x * 4 + (threadIdx.x >> 6);   // 0 .. B*L-1
  int lane = threadIdx.x & 63;
  const float* x = lat + (size_t)row * C_;
  float s1 = 0.f, s2 = 0.f, sd = 0.f, sgc = 0.f, sbc = 0.f;
  #pragma unroll
  for (int i = 0; i < 2; i++){
    int c = i * 256 + lane * 4;
    float4 xv = *(const float4*)(x  + c);
    float4 gv = *(const float4*)(g1 + c);
    float4 bv = *(const float4*)(b1 + c);
    float4 wv = *(const float4*)(cw + c);
    s1 += xv.x + xv.y + xv.z + xv.w;
    s2 += xv.x*xv.x + xv.y*xv.y + xv.z*xv.z + xv.w*xv.w;
    float gw0 = gv.x*wv.x, gw1 = gv.y*wv.y, gw2 = gv.z*wv.z, gw3 = gv.w*wv.w;
    sgc += gw0 + gw1 + gw2 + gw3;
    sd  += xv.x*gw0 + xv.y*gw1 + xv.z*gw2 + xv.w*gw3;
    sbc += bv.x*wv.x + bv.y*wv.y + bv.z*wv.z + bv.w*wv.w;
  }
  s1 = waveReduceSum(s1);  s2 = waveReduceSum(s2);  sd = waveReduceSum(sd);
  sgc = waveReduceSum(sgc); sbc = waveReduceSum(sbc);
  if (lane == 0){
    float m    = s1 * (1.f / C_);
    float var  = s2 * (1.f / C_) - m * m;
    float rstd = rsqrtf(var + 1e-5f);
    scores[row] = (sd - m * sgc) * rstd + sbc + cbp[0];
  }
}

// ---------------- top-8 per batch, tie-break smaller index, sort asc ----------------
__global__ __launch_bounds__(256) void k_topk(const float* __restrict__ scores, int* __restrict__ idxout)
{
  __shared__ float sv[L_];
  __shared__ float rv_[4];
  __shared__ int   ri_[4];
  __shared__ int   chosen[SLOTS];
  int b = blockIdx.x, tid = threadIdx.x;
  for (int i = tid; i < L_; i += 256) sv[i] = scores[b * L_ + i];
  __syncthreads();
  for (int it = 0; it < SLOTS; it++){
    float best = -INFINITY; int bi = L_;
    for (int i = tid; i < L_; i += 256){
      float v = sv[i];
      if (v > best || (v == best && i < bi)){ best = v; bi = i; }
    }
    #pragma unroll
    for (int off = 32; off; off >>= 1){
      float ov = __shfl_down(best, off); int oi = __shfl_down(bi, off);
      if (ov > best || (ov == best && oi < bi)){ best = ov; bi = oi; }
    }
    if ((tid & 63) == 0){ rv_[tid >> 6] = best; ri_[tid >> 6] = bi; }
    __syncthreads();
    if (tid == 0){
      for (int w2 = 1; w2 < 4; w2++){
        if (rv_[w2] > best || (rv_[w2] == best && ri_[w2] < bi)){ best = rv_[w2]; bi = ri_[w2]; }
      }
      chosen[it] = bi;
      sv[bi] = -INFINITY;
    }
    __syncthreads();
  }
  if (tid == 0){
    for (int i = 0; i < SLOTS; i++){
      for (int j = i + 1; j < SLOTS; j++){
        if (chosen[j] < chosen[i]){ int t = chosen[i]; chosen[i] = chosen[j]; chosen[j] = t; }
      }
      idxout[b * SLOTS + i] = chosen[i];
    }
  }
}

// ---------------- carrier gather + LN2 (wave per carrier row) ----------------
__global__ __launch_bounds__(64) void k_carrier(
    const float* __restrict__ lat, const int* __restrict__ idx,
    const float* __restrict__ g2, const float* __restrict__ b2, float* __restrict__ out)
{
  int slot = blockIdx.x;            // b*8 + s
  int b = slot >> 3, s = slot & 7;
  int lane = threadIdx.x;
  int l = idx[slot];
  const float* x = lat + ((size_t)b * L_ + l) * C_;
  float xs[8];
  float s1 = 0.f, s2 = 0.f;
  #pragma unroll
  for (int i = 0; i < 2; i++){
    float4 v = *(const float4*)(x + i * 256 + lane * 4);
    xs[i*4+0] = v.x; xs[i*4+1] = v.y; xs[i*4+2] = v.z; xs[i*4+3] = v.w;
    s1 += v.x + v.y + v.z + v.w;
    s2 += v.x*v.x + v.y*v.y + v.z*v.z + v.w*v.w;
  }
  s1 = waveReduceSum(s1); s2 = waveReduceSum(s2);
  float m = s1 * (1.f / C_);
  float rstd = rsqrtf(s2 * (1.f / C_) - m * m + 1e-5f);
  float* o = out + ((size_t)b * LM_ + s) * C_;
  #pragma unroll
  for (int i = 0; i < 2; i++){
    int c = i * 256 + lane * 4;
    float4 gv = *(const float4*)(g2 + c);
    float4 bv = *(const float4*)(b2 + c);
    float4 ov;
    ov.x = (xs[i*4+0] - m) * rstd * gv.x + bv.x;
    ov.y = (xs[i*4+1] - m) * rstd * gv.y + bv.y;
    ov.z = (xs[i*4+2] - m) * rstd * gv.z + bv.z;
    ov.w = (xs[i*4+3] - m) * rstd * gv.w + bv.w;
    *(float4*)(o + c) = ov;
  }
}

// ---------------- LN1 (recomputed) + depthwise conv stride2 + exact GELU ----------------
__global__ __launch_bounds__(256) void k_conv(
    const float* __restrict__ lat, const float* __restrict__ g1, const float* __restrict__ b1,
    const float* __restrict__ dw, const float* __restrict__ db, float* __restrict__ hbuf)
{
  __shared__ float rowbuf[3][C_];
  __shared__ float mrs[3][2];
  int bt = blockIdx.x;
  int b = bt >> 11;
  int t = bt & (LO_ - 1);
  int tid = threadIdx.x;
  #pragma unroll
  for (int r = 0; r < 3; r++){
    int l = 2 * t - 1 + r;                 // -1 only at t=0,r=0; max 4095
    float2 v;
    if (l >= 0){
      v = *(const float2*)(lat + ((size_t)b * L_ + l) * C_ + tid * 2);
    } else { v.x = 0.f; v.y = 0.f; }
    *(float2*)&rowbuf[r][tid * 2] = v;
  }
  __syncthreads();
  int w = tid >> 6, lane = tid & 63;
  if (w < 3){
    float s1 = 0.f, s2 = 0.f;
    #pragma unroll
    for (int i = 0; i < 8; i++){
      float v = rowbuf[w][lane + 64 * i];
      s1 += v; s2 += v * v;
    }
    s1 = waveReduceSum(s1); s2 = waveReduceSum(s2);
    if (lane == 0){
      float m = s1 * (1.f / C_);
      float var = s2 * (1.f / C_) - m * m;
      mrs[w][0] = m; mrs[w][1] = rsqrtf(var + 1e-5f);
    }
  }
  __syncthreads();
  bool v0 = (t > 0);   // t==0: left neighbor is conv zero-pad (pad applies to normalized!)
  float m0 = mrs[0][0], r0 = mrs[0][1];
  float m1 = mrs[1][0], r1 = mrs[1][1];
  float m2 = mrs[2][0], r2 = mrs[2][1];
  size_t base = ((size_t)b * LO_ + t) * C_;
  #pragma unroll
  for (int i = 0; i < 2; i++){
    int c = tid + i * 256;
    float g = g1[c], bb = b1[c];
    float n0v = v0 ? ((rowbuf[0][c] - m0) * r0 * g + bb) : 0.f;
    float n1v = (rowbuf[1][c] - m1) * r1 * g + bb;
    float n2v = (rowbuf[2][c] - m2) * r2 * g + bb;
    float hh = n0v * dw[c*3+0] + n1v * dw[c*3+1] + n2v * dw[c*3+2] + db[c];
    float ge = 0.5f * hh * (1.f + erff(hh * 0.70710678118654752440f));
    hbuf[base + c] = ge;
  }
}

// ---------------- fp32 tiled GEMM: reduced[m,o] = sum_c h[m,c]*pw[o,c] + pb[o] ----------------
__global__ __launch_bounds__(256) void k_gemm(
    const float* __restrict__ A, const float* __restrict__ Bw,
    const float* __restrict__ bias, float* __restrict__ Cout)
{
  __shared__ float As[16][64];
  __shared__ float Bs[16][64];
  int tid = threadIdx.x;
  int tx = tid & 15, ty = tid >> 4;
  int row0 = blockIdx.y * 64, col0 = blockIdx.x * 64;
  int lr = tid >> 2;          // 0..63 row within tile
  int lk = (tid & 3) * 4;     // k offset {0,4,8,12}
  const float* Ap = A  + (size_t)(row0 + lr) * C_ + lk;
  const float* Bp = Bw + (size_t)(col0 + lr) * C_ + lk;
  float acc[4][4] = {};
  for (int k0 = 0; k0 < C_; k0 += 16){
    float4 av = *(const float4*)(Ap + k0);
    float4 bv = *(const float4*)(Bp + k0);
    __syncthreads();
    As[lk+0][lr] = av.x; As[lk+1][lr] = av.y; As[lk+2][lr] = av.z; As[lk+3][lr] = av.w;
    Bs[lk+0][lr] = bv.x; Bs[lk+1][lr] = bv.y; Bs[lk+2][lr] = bv.z; Bs[lk+3][lr] = bv.w;
    __syncthreads();
    #pragma unroll
    for (int k = 0; k < 16; k++){
      float4 a  = *(const float4*)&As[k][ty * 4];
      float4 bq = *(const float4*)&Bs[k][tx * 4];
      float aa[4] = {a.x, a.y, a.z, a.w};
      float bb[4] = {bq.x, bq.y, bq.z, bq.w};
      #pragma unroll
      for (int i2 = 0; i2 < 4; i2++)
        #pragma unroll
        for (int j = 0; j < 4; j++)
          acc[i2][j] += aa[i2] * bb[j];
    }
  }
  #pragma unroll
  for (int i2 = 0; i2 < 4; i2++){
    int row = row0 + ty * 4 + i2;
    int col = col0 + tx * 4;
    float4 o;
    o.x = acc[i2][0] + bias[col+0];
    o.y = acc[i2][1] + bias[col+1];
    o.z = acc[i2][2] + bias[col+2];
    o.w = acc[i2][3] + bias[col+3];
    *(float4*)(Cout + (size_t)row * C_ + col) = o;
  }
}

// ---------------- pooled + gate + merge + LN2 (wave per output row) ----------------
__global__ __launch_bounds__(256) void k_epilogue(
    const float* __restrict__ red, const float* __restrict__ lat,
    const float* __restrict__ gw, const float* __restrict__ gbp,
    const float* __restrict__ g2, const float* __restrict__ b2,
    float* __restrict__ out, float* __restrict__ gateout)
{
  int row  = blockIdx.x * 4 + (threadIdx.x >> 6);   // b*2048 + l
  int lane = threadIdx.x & 63;
  int b = row >> 11, l = row & (LO_ - 1);
  const float* rr = red + (size_t)row * C_;
  const float* p0 = lat + ((size_t)b * L_ + 2 * l) * C_;
  const float* p1 = p0 + C_;
  float rv[8], pv[8];
  float lp = 0.f;
  #pragma unroll
  for (int i = 0; i < 2; i++){
    int c = i * 256 + lane * 4;
    float4 r4 = *(const float4*)(rr + c);
    float4 a4 = *(const float4*)(p0 + c);
    float4 b4 = *(const float4*)(p1 + c);
    float4 w1 = *(const float4*)(gw + c);
    float4 w2 = *(const float4*)(gw + C_ + c);
    float q0 = 0.5f * (a4.x + b4.x);
    float q1 = 0.5f * (a4.y + b4.y);
    float q2 = 0.5f * (a4.z + b4.z);
    float q3 = 0.5f * (a4.w + b4.w);
    rv[i*4+0] = r4.x; rv[i*4+1] = r4.y; rv[i*4+2] = r4.z; rv[i*4+3] = r4.w;
    pv[i*4+0] = q0;   pv[i*4+1] = q1;   pv[i*4+2] = q2;   pv[i*4+3] = q3;
    lp += r4.x*w1.x + r4.y*w1.y + r4.z*w1.z + r4.w*w1.w
        + q0*w2.x + q1*w2.y + q2*w2.z + q3*w2.w;
  }
  lp = waveReduceSum(lp);
  float gate = 0.5f + 0.5f / (1.f + expf(-(lp + gbp[0])));
  float mv[8];
  float s1 = 0.f, s2 = 0.f;
  #pragma unroll
  for (int j = 0; j < 8; j++){
    mv[j] = pv[j] + gate * (rv[j] - pv[j]);
    s1 += mv[j]; s2 += mv[j] * mv[j];
  }
  s1 = waveReduceSum(s1); s2 = waveReduceSum(s2);
  float m = s1 * (1.f / C_);
  float rstd = rsqrtf(s2 * (1.f / C_) - m * m + 1e-5f);
  float* o = out + ((size_t)b * LM_ + SLOTS + l) * C_;
  #pragma unroll
  for (int i = 0; i < 2; i++){
    int c = i * 256 + lane * 4;
    float4 gv = *(const float4*)(g2 + c);
    float4 bv = *(const float4*)(b2 + c);
    float4 ov;
    ov.x = (mv[i*4+0] - m) * rstd * gv.x + bv.x;
    ov.y = (mv[i*4+1] - m) * rstd * gv.y + bv.y;
    ov.z = (mv[i*4+2] - m) * rstd * gv.z + bv.z;
    ov.w = (mv[i*4+3] - m) * rstd * gv.w + bv.w;
    *(float4*)(o + c) = ov;
  }
  if (lane == 0) gateout[b * LO_ + l] = gate;
}

extern "C" void kernel_launch(void* const* d_in, const int* in_sizes, int n_in,
                              void* d_out, int out_size, void* d_ws, size_t ws_size,
                              hipStream_t stream)
{
  const float* lat = (const float*)d_in[0];
  const float* g1  = (const float*)d_in[1];
  const float* b1  = (const float*)d_in[2];
  const float* dw  = (const float*)d_in[3];
  const float* db  = (const float*)d_in[4];
  const float* pw  = (const float*)d_in[5];
  const float* pb  = (const float*)d_in[6];
  const float* gw  = (const float*)d_in[7];
  const float* gb  = (const float*)d_in[8];
  const float* cw  = (const float*)d_in[9];
  const float* cb  = (const float*)d_in[10];
  const float* g2  = (const float*)d_in[11];
  const float* b2  = (const float*)d_in[12];

  float* out = (float*)d_out;
  float* gateout = out + (size_t)B_ * LM_ * C_;

  float* ws     = (float*)d_ws;
  float* hbuf   = ws;                                  // B*LO*C = 8388608 floats
  float* red    = ws + (size_t)B_ * LO_ * C_;          // 8388608 floats
  float* scores = red + (size_t)B_ * LO_ * C_;         // B*L = 32768 floats
  int*   idx    = (int*)(scores + (size_t)B_ * L_);    // 64 ints

  hipLaunchKernelGGL(k_scores, dim3(B_ * L_ / 4), dim3(256), 0, stream, lat, g1, b1, cw, cb, scores);
  hipLaunchKernelGGL(k_topk, dim3(B_), dim3(256), 0, stream, scores, idx);
  hipLaunchKernelGGL(k_carrier, dim3(B_ * SLOTS), dim3(64), 0, stream, lat, idx, g2, b2, out);
  hipLaunchKernelGGL(k_conv, dim3(B_ * LO_), dim3(256), 0, stream, lat, g1, b1, dw, db, hbuf);
  hipLaunchKernelGGL(k_gemm, dim3(C_ / 64, B_ * LO_ / 64), dim3(256), 0, stream, hbuf, pw, pb, red);
  hipLaunchKernelGGL(k_epilogue, dim3(B_ * LO_ / 4), dim3(256), 0, stream, red, lat, gw, gb, g2, b2, out, gateout);
}

// Round 2
// 97.001 us; speedup vs baseline: 2.1762x; 2.1762x over previous
//
#include <hip/hip_runtime.h>
#include <hip/hip_bf16.h>
#include <math.h>

#define B_ 8
#define L_ 4096
#define C_ 512
#define LO_ 2048   // L/2
#define SLOTS 8
#define LM_ 2056   // SLOTS + LO_

typedef __attribute__((ext_vector_type(8))) short bf16x8;
typedef __attribute__((ext_vector_type(4))) float f32x4;
typedef unsigned short ushort_t;

__device__ __forceinline__ float waveReduceSum(float v){
  #pragma unroll
  for (int off = 32; off; off >>= 1) v += __shfl_xor(v, off);
  return v;
}

__device__ __forceinline__ unsigned short f2bf(float f){
  unsigned u = __float_as_uint(f);
  u += 0x7fffu + ((u >> 16) & 1u);   // RNE (inputs well-behaved, no NaN)
  return (unsigned short)(u >> 16);
}
__device__ __forceinline__ float bf2f(unsigned short b){
  return __uint_as_float(((unsigned)b) << 16);
}

#define GLOAD_LDS16(g, l) __builtin_amdgcn_global_load_lds( \
    (__attribute__((address_space(1))) void*)(g), \
    (__attribute__((address_space(3))) void*)(l), 16, 0, 0)

// ---------------- pw_w fp32 -> bf16 ----------------
__global__ __launch_bounds__(256) void k_cast(const float* __restrict__ src, ushort_t* __restrict__ dst){
  int i = (blockIdx.x * 256 + threadIdx.x) * 4;   // 256 blocks covers 262144
  float4 v = *(const float4*)(src + i);
  ushort4 o;
  o.x = f2bf(v.x); o.y = f2bf(v.y); o.z = f2bf(v.z); o.w = f2bf(v.w);
  *(ushort4*)(dst + i) = o;
}

// ---------------- LN1 stats + carrier score (fused, wave per row) ----------------
__global__ __launch_bounds__(256) void k_scores(
    const float* __restrict__ lat, const float* __restrict__ g1, const float* __restrict__ b1,
    const float* __restrict__ cw, const float* __restrict__ cbp,
    float* __restrict__ scores, float* __restrict__ mrow, float* __restrict__ rrow)
{
  int row  = blockIdx.x * 4 + (threadIdx.x >> 6);   // 0 .. B*L-1
  int lane = threadIdx.x & 63;
  const float* x = lat + (size_t)row * C_;
  float s1 = 0.f, s2 = 0.f, sd = 0.f, sgc = 0.f, sbc = 0.f;
  #pragma unroll
  for (int i = 0; i < 2; i++){
    int c = i * 256 + lane * 4;
    float4 xv = *(const float4*)(x  + c);
    float4 gv = *(const float4*)(g1 + c);
    float4 bv = *(const float4*)(b1 + c);
    float4 wv = *(const float4*)(cw + c);
    s1 += xv.x + xv.y + xv.z + xv.w;
    s2 += xv.x*xv.x + xv.y*xv.y + xv.z*xv.z + xv.w*xv.w;
    float gw0 = gv.x*wv.x, gw1 = gv.y*wv.y, gw2 = gv.z*wv.z, gw3 = gv.w*wv.w;
    sgc += gw0 + gw1 + gw2 + gw3;
    sd  += xv.x*gw0 + xv.y*gw1 + xv.z*gw2 + xv.w*gw3;
    sbc += bv.x*wv.x + bv.y*wv.y + bv.z*wv.z + bv.w*wv.w;
  }
  s1 = waveReduceSum(s1);  s2 = waveReduceSum(s2);  sd = waveReduceSum(sd);
  sgc = waveReduceSum(sgc); sbc = waveReduceSum(sbc);
  if (lane == 0){
    float m    = s1 * (1.f / C_);
    float var  = s2 * (1.f / C_) - m * m;
    float rstd = rsqrtf(var + 1e-5f);
    scores[row] = (sd - m * sgc) * rstd + sbc + cbp[0];
    mrow[row] = m;
    rrow[row] = rstd;
  }
}

// ---------------- top-8 per batch, tie-break smaller index, sort asc ----------------
__global__ __launch_bounds__(256) void k_topk(const float* __restrict__ scores, int* __restrict__ idxout)
{
  __shared__ float sv[L_];
  __shared__ float rv_[4];
  __shared__ int   ri_[4];
  __shared__ int   chosen[SLOTS];
  int b = blockIdx.x, tid = threadIdx.x;
  for (int i = tid; i < L_; i += 256) sv[i] = scores[b * L_ + i];
  __syncthreads();
  for (int it = 0; it < SLOTS; it++){
    float best = -INFINITY; int bi = L_;
    for (int i = tid; i < L_; i += 256){
      float v = sv[i];
      if (v > best || (v == best && i < bi)){ best = v; bi = i; }
    }
    #pragma unroll
    for (int off = 32; off; off >>= 1){
      float ov = __shfl_down(best, off); int oi = __shfl_down(bi, off);
      if (ov > best || (ov == best && oi < bi)){ best = ov; bi = oi; }
    }
    if ((tid & 63) == 0){ rv_[tid >> 6] = best; ri_[tid >> 6] = bi; }
    __syncthreads();
    if (tid == 0){
      for (int w2 = 1; w2 < 4; w2++){
        if (rv_[w2] > best || (rv_[w2] == best && ri_[w2] < bi)){ best = rv_[w2]; bi = ri_[w2]; }
      }
      chosen[it] = bi;
      sv[bi] = -INFINITY;
    }
    __syncthreads();
  }
  if (tid == 0){
    for (int i = 0; i < SLOTS; i++){
      for (int j = i + 1; j < SLOTS; j++){
        if (chosen[j] < chosen[i]){ int t = chosen[i]; chosen[i] = chosen[j]; chosen[j] = t; }
      }
      idxout[b * SLOTS + i] = chosen[i];
    }
  }
}

// ---------------- carrier gather + LN2 (wave per carrier row) ----------------
__global__ __launch_bounds__(64) void k_carrier(
    const float* __restrict__ lat, const int* __restrict__ idx,
    const float* __restrict__ g2, const float* __restrict__ b2, float* __restrict__ out)
{
  int slot = blockIdx.x;            // b*8 + s
  int b = slot >> 3, s = slot & 7;
  int lane = threadIdx.x;
  int l = idx[slot];
  const float* x = lat + ((size_t)b * L_ + l) * C_;
  float xs[8];
  float s1 = 0.f, s2 = 0.f;
  #pragma unroll
  for (int i = 0; i < 2; i++){
    float4 v = *(const float4*)(x + i * 256 + lane * 4);
    xs[i*4+0] = v.x; xs[i*4+1] = v.y; xs[i*4+2] = v.z; xs[i*4+3] = v.w;
    s1 += v.x + v.y + v.z + v.w;
    s2 += v.x*v.x + v.y*v.y + v.z*v.z + v.w*v.w;
  }
  s1 = waveReduceSum(s1); s2 = waveReduceSum(s2);
  float m = s1 * (1.f / C_);
  float rstd = rsqrtf(s2 * (1.f / C_) - m * m + 1e-5f);
  float* o = out + ((size_t)b * LM_ + s) * C_;
  #pragma unroll
  for (int i = 0; i < 2; i++){
    int c = i * 256 + lane * 4;
    float4 gv = *(const float4*)(g2 + c);
    float4 bv = *(const float4*)(b2 + c);
    float4 ov;
    ov.x = (xs[i*4+0] - m) * rstd * gv.x + bv.x;
    ov.y = (xs[i*4+1] - m) * rstd * gv.y + bv.y;
    ov.z = (xs[i*4+2] - m) * rstd * gv.z + bv.z;
    ov.w = (xs[i*4+3] - m) * rstd * gv.w + bv.w;
    *(float4*)(o + c) = ov;
  }
}

// ---------------- LN1(precomp stats) + depthwise conv stride2 + exact GELU + pooled ----------------
// block: 256 threads = 2 channels/thread, 4 outputs per block (9 source rows)
__global__ __launch_bounds__(256) void k_conv(
    const float* __restrict__ lat, const float* __restrict__ g1, const float* __restrict__ b1,
    const float* __restrict__ dw, const float* __restrict__ db,
    const float* __restrict__ mrow, const float* __restrict__ rrow,
    ushort_t* __restrict__ hbuf, ushort_t* __restrict__ pooled)
{
  int blk = blockIdx.x;            // b * 512 + tchunk
  int b = blk >> 9;
  int t0 = (blk & 511) * 4;
  int c = threadIdx.x * 2;
  float2 xr[9];
  float mr[9], rr[9];
  const float* base = lat + ((size_t)(b * L_ + 2*t0 - 1)) * C_ + c;
  int rowbase = b * L_ + 2*t0 - 1;
  #pragma unroll
  for (int r = 0; r < 9; r++){
    int l = 2*t0 - 1 + r;
    if (l >= 0){
      xr[r] = *(const float2*)(base + (size_t)r * C_);
      mr[r] = mrow[rowbase + r];
      rr[r] = rrow[rowbase + r];
    } else { xr[r].x = 0.f; xr[r].y = 0.f; mr[r] = 0.f; rr[r] = 0.f; }
  }
  float g0 = g1[c], g1v = g1[c+1];
  float bb0 = b1[c], bb1 = b1[c+1];
  float w00 = dw[c*3+0], w01 = dw[c*3+1], w02 = dw[c*3+2];
  float w10 = dw[(c+1)*3+0], w11 = dw[(c+1)*3+1], w12 = dw[(c+1)*3+2];
  float db0 = db[c], db1 = db[c+1];
  bool pad0 = (t0 == 0);
  #pragma unroll
  for (int t = 0; t < 4; t++){
    int rl = 2*t, rm = 2*t+1, rrgt = 2*t+2;
    float n0x, n0y;
    if (pad0 && t == 0){ n0x = 0.f; n0y = 0.f; }
    else {
      n0x = (xr[rl].x - mr[rl]) * rr[rl] * g0 + bb0;
      n0y = (xr[rl].y - mr[rl]) * rr[rl] * g1v + bb1;
    }
    float n1x = (xr[rm].x - mr[rm]) * rr[rm] * g0 + bb0;
    float n1y = (xr[rm].y - mr[rm]) * rr[rm] * g1v + bb1;
    float n2x = (xr[rrgt].x - mr[rrgt]) * rr[rrgt] * g0 + bb0;
    float n2y = (xr[rrgt].y - mr[rrgt]) * rr[rrgt] * g1v + bb1;
    float h0 = n0x * w00 + n1x * w01 + n2x * w02 + db0;
    float h1 = n0y * w10 + n1y * w11 + n2y * w12 + db1;
    float ge0 = 0.5f * h0 * (1.f + erff(h0 * 0.70710678118654752440f));
    float ge1 = 0.5f * h1 * (1.f + erff(h1 * 0.70710678118654752440f));
    size_t oidx = ((size_t)(b * LO_ + t0 + t)) * C_ + c;
    ushort2 hv; hv.x = f2bf(ge0); hv.y = f2bf(ge1);
    *(ushort2*)(hbuf + oidx) = hv;
    // pooled = mean of raw latent rows 2T, 2T+1  (r = 2t+1, 2t+2)
    float p0 = 0.5f * (xr[rm].x + xr[rrgt].x);
    float p1 = 0.5f * (xr[rm].y + xr[rrgt].y);
    ushort2 pv; pv.x = f2bf(p0); pv.y = f2bf(p1);
    *(ushort2*)(pooled + oidx) = pv;
  }
}

// ---------------- bf16 MFMA GEMM: red[m,o] = sum_c h[m,c]*pw[o,c] + pb[o] ----------------
// 128x128 tile, BK=32, 4 waves each computing 64x64 (4x4 frags of 16x16x32)
__global__ __launch_bounds__(256) void k_gemm(
    const ushort_t* __restrict__ A, const ushort_t* __restrict__ Bw,
    const float* __restrict__ bias, float* __restrict__ Cout)
{
  __shared__ short As[128][32];
  __shared__ short Bs[128][32];
  int tid = threadIdx.x;
  int w = tid >> 6, lane = tid & 63;
  int row0 = blockIdx.y * 128, col0 = blockIdx.x * 128;
  int wr = (w >> 1) * 64, wc = (w & 1) * 64;
  int srow = lane >> 2;          // 0..15
  int scol = (lane & 3) * 8;     // elem offset within 32-k
  int fr = lane & 15, kq = (lane >> 4) * 8;

  f32x4 acc[4][4];
  #pragma unroll
  for (int m = 0; m < 4; m++)
    #pragma unroll
    for (int n = 0; n < 4; n++)
      acc[m][n] = (f32x4){0.f, 0.f, 0.f, 0.f};

  for (int k0 = 0; k0 < C_; k0 += 32){
    __syncthreads();               // prev iter's reads done before overwrite
    #pragma unroll
    for (int j = 0; j < 2; j++){
      int i = 2*w + j;             // 0..7: 16-row stripe
      GLOAD_LDS16(A  + (size_t)(row0 + 16*i + srow) * C_ + k0 + scol, &As[16*i][0]);
      GLOAD_LDS16(Bw + (size_t)(col0 + 16*i + srow) * C_ + k0 + scol, &Bs[16*i][0]);
    }
    __syncthreads();               // drains vmcnt(0)
    bf16x8 af[4], bfr[4];
    #pragma unroll
    for (int m = 0; m < 4; m++) af[m]  = *(const bf16x8*)&As[wr + m*16 + fr][kq];
    #pragma unroll
    for (int n = 0; n < 4; n++) bfr[n] = *(const bf16x8*)&Bs[wc + n*16 + fr][kq];
    #pragma unroll
    for (int m = 0; m < 4; m++)
      #pragma unroll
      for (int n = 0; n < 4; n++)
        acc[m][n] = __builtin_amdgcn_mfma_f32_16x16x32_bf16(af[m], bfr[n], acc[m][n], 0, 0, 0);
  }

  // C/D layout: col = lane&15, row = (lane>>4)*4 + j
  int cq = lane & 15, rq = (lane >> 4) * 4;
  #pragma unroll
  for (int n = 0; n < 4; n++){
    int col = col0 + wc + n*16 + cq;
    float bv = bias[col];
    #pragma unroll
    for (int m = 0; m < 4; m++){
      #pragma unroll
      for (int j = 0; j < 4; j++){
        int row = row0 + wr + m*16 + rq + j;
        Cout[(size_t)row * C_ + col] = acc[m][n][j] + bv;
      }
    }
  }
}

// ---------------- pooled + gate + merge + LN2 (wave per output row) ----------------
__global__ __launch_bounds__(256) void k_epilogue(
    const float* __restrict__ red, const ushort_t* __restrict__ pooled,
    const float* __restrict__ gw, const float* __restrict__ gbp,
    const float* __restrict__ g2, const float* __restrict__ b2,
    float* __restrict__ out, float* __restrict__ gateout)
{
  int row  = blockIdx.x * 4 + (threadIdx.x >> 6);   // b*2048 + l
  int lane = threadIdx.x & 63;
  int b = row >> 11, l = row & (LO_ - 1);
  const float* rr = red + (size_t)row * C_;
  const ushort_t* pp = pooled + (size_t)row * C_;
  float rv[8], pv[8];
  float lp = 0.f;
  #pragma unroll
  for (int i = 0; i < 2; i++){
    int c = i * 256 + lane * 4;
    float4 r4 = *(const float4*)(rr + c);
    ushort4 p4 = *(const ushort4*)(pp + c);
    float4 w1 = *(const float4*)(gw + c);
    float4 w2 = *(const float4*)(gw + C_ + c);
    float q0 = bf2f(p4.x), q1 = bf2f(p4.y), q2 = bf2f(p4.z), q3 = bf2f(p4.w);
    rv[i*4+0] = r4.x; rv[i*4+1] = r4.y; rv[i*4+2] = r4.z; rv[i*4+3] = r4.w;
    pv[i*4+0] = q0;   pv[i*4+1] = q1;   pv[i*4+2] = q2;   pv[i*4+3] = q3;
    lp += r4.x*w1.x + r4.y*w1.y + r4.z*w1.z + r4.w*w1.w
        + q0*w2.x + q1*w2.y + q2*w2.z + q3*w2.w;
  }
  lp = waveReduceSum(lp);
  float gate = 0.5f + 0.5f / (1.f + expf(-(lp + gbp[0])));
  float mv[8];
  float s1 = 0.f, s2 = 0.f;
  #pragma unroll
  for (int j = 0; j < 8; j++){
    mv[j] = pv[j] + gate * (rv[j] - pv[j]);
    s1 += mv[j]; s2 += mv[j] * mv[j];
  }
  s1 = waveReduceSum(s1); s2 = waveReduceSum(s2);
  float m = s1 * (1.f / C_);
  float rstd = rsqrtf(s2 * (1.f / C_) - m * m + 1e-5f);
  float* o = out + ((size_t)(b * LM_ + SLOTS + l)) * C_;
  #pragma unroll
  for (int i = 0; i < 2; i++){
    int c = i * 256 + lane * 4;
    float4 gv = *(const float4*)(g2 + c);
    float4 bv = *(const float4*)(b2 + c);
    float4 ov;
    ov.x = (mv[i*4+0] - m) * rstd * gv.x + bv.x;
    ov.y = (mv[i*4+1] - m) * rstd * gv.y + bv.y;
    ov.z = (mv[i*4+2] - m) * rstd * gv.z + bv.z;
    ov.w = (mv[i*4+3] - m) * rstd * gv.w + bv.w;
    *(float4*)(o + c) = ov;
  }
  if (lane == 0) gateout[b * LO_ + l] = gate;
}

extern "C" void kernel_launch(void* const* d_in, const int* in_sizes, int n_in,
                              void* d_out, int out_size, void* d_ws, size_t ws_size,
                              hipStream_t stream)
{
  const float* lat = (const float*)d_in[0];
  const float* g1  = (const float*)d_in[1];
  const float* b1  = (const float*)d_in[2];
  const float* dw  = (const float*)d_in[3];
  const float* db  = (const float*)d_in[4];
  const float* pw  = (const float*)d_in[5];
  const float* pb  = (const float*)d_in[6];
  const float* gw  = (const float*)d_in[7];
  const float* gb  = (const float*)d_in[8];
  const float* cw  = (const float*)d_in[9];
  const float* cb  = (const float*)d_in[10];
  const float* g2  = (const float*)d_in[11];
  const float* b2  = (const float*)d_in[12];

  float* out = (float*)d_out;
  float* gateout = out + (size_t)B_ * LM_ * C_;

  const size_t NHL = (size_t)B_ * LO_ * C_;   // 8388608
  ushort_t* hbuf   = (ushort_t*)d_ws;
  ushort_t* pooled = hbuf + NHL;
  float*    red    = (float*)(pooled + NHL);
  ushort_t* pwb    = (ushort_t*)(red + NHL);
  float*    scores = (float*)(pwb + (size_t)C_ * C_);
  float*    mrow   = scores + (size_t)B_ * L_;
  float*    rrow   = mrow + (size_t)B_ * L_;
  int*      idx    = (int*)(rrow + (size_t)B_ * L_);

  hipLaunchKernelGGL(k_cast,    dim3(C_ * C_ / 1024), dim3(256), 0, stream, pw, pwb);
  hipLaunchKernelGGL(k_scores,  dim3(B_ * L_ / 4), dim3(256), 0, stream, lat, g1, b1, cw, cb, scores, mrow, rrow);
  hipLaunchKernelGGL(k_topk,    dim3(B_), dim3(256), 0, stream, scores, idx);
  hipLaunchKernelGGL(k_carrier, dim3(B_ * SLOTS), dim3(64), 0, stream, lat, idx, g2, b2, out);
  hipLaunchKernelGGL(k_conv,    dim3(B_ * LO_ / 4), dim3(256), 0, stream, lat, g1, b1, dw, db, mrow, rrow, hbuf, pooled);
  hipLaunchKernelGGL(k_gemm,    dim3(C_ / 128, B_ * LO_ / 128), dim3(256), 0, stream, hbuf, pwb, pb, red);
  hipLaunchKernelGGL(k_epilogue,dim3(B_ * LO_ / 4), dim3(256), 0, stream, red, pooled, gw, gb, g2, b2, out, gateout);
}

// Round 3
// 95.138 us; speedup vs baseline: 2.2188x; 1.0196x over previous
//
#include <hip/hip_runtime.h>
#include <hip/hip_bf16.h>
#include <math.h>

#define B_ 8
#define L_ 4096
#define C_ 512
#define LO_ 2048   // L/2
#define SLOTS 8
#define LM_ 2056   // SLOTS + LO_

typedef __attribute__((ext_vector_type(8))) short bf16x8;
typedef __attribute__((ext_vector_type(4))) float f32x4;
typedef unsigned short ushort_t;

__device__ __forceinline__ float waveReduceSum(float v){
  #pragma unroll
  for (int off = 32; off; off >>= 1) v += __shfl_xor(v, off);
  return v;
}

__device__ __forceinline__ unsigned short f2bf(float f){
  unsigned u = __float_as_uint(f);
  u += 0x7fffu + ((u >> 16) & 1u);   // RNE
  return (unsigned short)(u >> 16);
}
__device__ __forceinline__ float bf2f(unsigned short b){
  return __uint_as_float(((unsigned)b) << 16);
}

#define GLOAD_LDS16(g, l) __builtin_amdgcn_global_load_lds( \
    (__attribute__((address_space(1))) void*)(g), \
    (__attribute__((address_space(3))) void*)(l), 16, 0, 0)

// ---------------- pw_w fp32 -> bf16 ----------------
__global__ __launch_bounds__(256) void k_cast(const float* __restrict__ src, ushort_t* __restrict__ dst){
  int i = (blockIdx.x * 256 + threadIdx.x) * 4;
  float4 v = *(const float4*)(src + i);
  ushort4 o;
  o.x = f2bf(v.x); o.y = f2bf(v.y); o.z = f2bf(v.z); o.w = f2bf(v.w);
  *(ushort4*)(dst + i) = o;
}

// ---------------- fused: LN1 stats (in-block) + carrier score + depthwise conv
//                  stride2 + exact GELU + pooled, 4 outputs (9 source rows) per block
__global__ __launch_bounds__(256) void k_conv(
    const float* __restrict__ lat, const float* __restrict__ g1, const float* __restrict__ b1,
    const float* __restrict__ dw, const float* __restrict__ db,
    const float* __restrict__ cw, const float* __restrict__ cbp,
    ushort_t* __restrict__ hbuf, ushort_t* __restrict__ pooled, float* __restrict__ scores)
{
  __shared__ float red_[4][32];
  __shared__ float tot_[32];
  int blk = blockIdx.x;            // b * 512 + chunk
  int b = blk >> 9;
  int chunk = blk & 511;
  int t0 = chunk * 4;
  int tid = threadIdx.x;
  int c = tid * 2;
  int lbase = 8 * chunk - 1;       // in-batch row of r=0 (may be -1)

  float2 xr[9];
  #pragma unroll
  for (int r = 0; r < 9; r++){
    int l = lbase + r;
    if (l >= 0){
      xr[r] = *(const float2*)(lat + ((size_t)(b * L_ + l)) * C_ + c);
    } else { xr[r].x = 0.f; xr[r].y = 0.f; }
  }
  float g0 = g1[c], g1v = g1[c+1];
  float bb0 = b1[c], bb1 = b1[c+1];
  float cw0 = cw[c], cw1 = cw[c+1];

  // per-row partials over this thread's 2 channels
  float s1l[9], s2l[9], sdl[9];
  #pragma unroll
  for (int r = 0; r < 9; r++){
    s1l[r] = xr[r].x + xr[r].y;
    s2l[r] = xr[r].x*xr[r].x + xr[r].y*xr[r].y;
    sdl[r] = xr[r].x*g0*cw0 + xr[r].y*g1v*cw1;
  }
  float sgcl = g0*cw0 + g1v*cw1;
  float sbcl = bb0*cw0 + bb1*cw1;
  #pragma unroll
  for (int r = 0; r < 9; r++){
    s1l[r] = waveReduceSum(s1l[r]);
    s2l[r] = waveReduceSum(s2l[r]);
    sdl[r] = waveReduceSum(sdl[r]);
  }
  sgcl = waveReduceSum(sgcl);
  sbcl = waveReduceSum(sbcl);
  int wv = tid >> 6, lane = tid & 63;
  if (lane == 0){
    #pragma unroll
    for (int r = 0; r < 9; r++){
      red_[wv][r]      = s1l[r];
      red_[wv][9 + r]  = s2l[r];
      red_[wv][18 + r] = sdl[r];
    }
    red_[wv][27] = sgcl;
    red_[wv][28] = sbcl;
  }
  __syncthreads();
  if (tid < 29) tot_[tid] = red_[0][tid] + red_[1][tid] + red_[2][tid] + red_[3][tid];
  __syncthreads();

  float mr[9], rr[9];
  #pragma unroll
  for (int r = 0; r < 9; r++){
    mr[r] = tot_[r] * (1.f / C_);
    float var = tot_[9 + r] * (1.f / C_) - mr[r] * mr[r];
    rr[r] = rsqrtf(var + 1e-5f);
  }
  if (tid >= 1 && tid <= 8){
    int r = tid;
    float sc = (tot_[18 + r] - mr[r] * tot_[27]) * rr[r] + tot_[28] + cbp[0];
    scores[b * L_ + lbase + r] = sc;
  }

  float w00 = dw[c*3+0], w01 = dw[c*3+1], w02 = dw[c*3+2];
  float w10 = dw[(c+1)*3+0], w11 = dw[(c+1)*3+1], w12 = dw[(c+1)*3+2];
  float db0 = db[c], db1 = db[c+1];
  bool pad0 = (chunk == 0);
  #pragma unroll
  for (int t = 0; t < 4; t++){
    int rl = 2*t, rm = 2*t+1, rrg = 2*t+2;
    float n0x, n0y;
    if (pad0 && t == 0){ n0x = 0.f; n0y = 0.f; }
    else {
      n0x = (xr[rl].x - mr[rl]) * rr[rl] * g0 + bb0;
      n0y = (xr[rl].y - mr[rl]) * rr[rl] * g1v + bb1;
    }
    float n1x = (xr[rm].x - mr[rm]) * rr[rm] * g0 + bb0;
    float n1y = (xr[rm].y - mr[rm]) * rr[rm] * g1v + bb1;
    float n2x = (xr[rrg].x - mr[rrg]) * rr[rrg] * g0 + bb0;
    float n2y = (xr[rrg].y - mr[rrg]) * rr[rrg] * g1v + bb1;
    float h0 = n0x * w00 + n1x * w01 + n2x * w02 + db0;
    float h1 = n0y * w10 + n1y * w11 + n2y * w12 + db1;
    float ge0 = 0.5f * h0 * (1.f + erff(h0 * 0.70710678118654752440f));
    float ge1 = 0.5f * h1 * (1.f + erff(h1 * 0.70710678118654752440f));
    size_t oidx = ((size_t)(b * LO_ + t0 + t)) * C_ + c;
    ushort2 hv; hv.x = f2bf(ge0); hv.y = f2bf(ge1);
    *(ushort2*)(hbuf + oidx) = hv;
    float p0 = 0.5f * (xr[rm].x + xr[rrg].x);
    float p1 = 0.5f * (xr[rm].y + xr[rrg].y);
    ushort2 pv; pv.x = f2bf(p0); pv.y = f2bf(p1);
    *(ushort2*)(pooled + oidx) = pv;
  }
}

// ---------------- top-k stage 1: top-8 of each 512-chunk (64 blocks) ----------------
__global__ __launch_bounds__(256) void k_topk1(
    const float* __restrict__ scores, float* __restrict__ cand_v, int* __restrict__ cand_i)
{
  __shared__ float sv[512];
  __shared__ float rv_[4];
  __shared__ int   ri_[4];
  int blk = blockIdx.x;          // b*8 + chunk
  int base = blk * 512;
  int tid = threadIdx.x;
  sv[tid] = scores[base + tid];
  sv[tid + 256] = scores[base + tid + 256];
  __syncthreads();
  int wv = tid >> 6, lane = tid & 63;
  for (int it = 0; it < SLOTS; it++){
    float v0 = sv[tid], v1 = sv[tid + 256];
    float best; int bi;
    if (v0 >= v1){ best = v0; bi = tid; } else { best = v1; bi = tid + 256; }
    #pragma unroll
    for (int off = 32; off; off >>= 1){
      float ov = __shfl_xor(best, off); int oi = __shfl_xor(bi, off);
      if (ov > best || (ov == best && oi < bi)){ best = ov; bi = oi; }
    }
    if (lane == 0){ rv_[wv] = best; ri_[wv] = bi; }
    __syncthreads();
    if (tid == 0){
      for (int w2 = 1; w2 < 4; w2++){
        if (rv_[w2] > best || (rv_[w2] == best && ri_[w2] < bi)){ best = rv_[w2]; bi = ri_[w2]; }
      }
      cand_v[blk * 8 + it] = best;
      cand_i[blk * 8 + it] = base + bi;
      sv[bi] = -INFINITY;
    }
    __syncthreads();
  }
}

// ---------------- top-k stage 2 (select 8 of 64) + carrier gather + LN2 ----------------
__global__ __launch_bounds__(256) void k_topk2(
    const float* __restrict__ cand_v, const int* __restrict__ cand_i,
    const float* __restrict__ lat,
    const float* __restrict__ g2, const float* __restrict__ b2, float* __restrict__ out)
{
  __shared__ int chosen[SLOTS];
  int b = blockIdx.x, tid = threadIdx.x;
  if (tid < 64){
    float v = cand_v[b * 64 + tid];
    int  idx = cand_i[b * 64 + tid];
    for (int it = 0; it < SLOTS; it++){
      float best = v; int bi = idx;
      #pragma unroll
      for (int off = 32; off; off >>= 1){
        float ov = __shfl_xor(best, off); int oi = __shfl_xor(bi, off);
        if (ov > best || (ov == best && oi < bi)){ best = ov; bi = oi; }
      }
      if (tid == 0) chosen[it] = bi;
      if (idx == bi) v = -INFINITY;
    }
  }
  __syncthreads();
  if (tid == 0){
    for (int i = 0; i < SLOTS; i++)
      for (int j = i + 1; j < SLOTS; j++)
        if (chosen[j] < chosen[i]){ int t = chosen[i]; chosen[i] = chosen[j]; chosen[j] = t; }
  }
  __syncthreads();
  int wv = tid >> 6, lane = tid & 63;
  for (int s = wv; s < SLOTS; s += 4){
    int l = chosen[s] - b * L_;          // chosen holds global score index = b*L + row
    const float* x = lat + ((size_t)(b * L_ + l)) * C_;
    float xs[8];
    float s1 = 0.f, s2 = 0.f;
    #pragma unroll
    for (int i = 0; i < 2; i++){
      float4 vv = *(const float4*)(x + i * 256 + lane * 4);
      xs[i*4+0] = vv.x; xs[i*4+1] = vv.y; xs[i*4+2] = vv.z; xs[i*4+3] = vv.w;
      s1 += vv.x + vv.y + vv.z + vv.w;
      s2 += vv.x*vv.x + vv.y*vv.y + vv.z*vv.z + vv.w*vv.w;
    }
    s1 = waveReduceSum(s1); s2 = waveReduceSum(s2);
    float m = s1 * (1.f / C_);
    float rstd = rsqrtf(s2 * (1.f / C_) - m * m + 1e-5f);
    float* o = out + ((size_t)(b * LM_ + s)) * C_;
    #pragma unroll
    for (int i = 0; i < 2; i++){
      int cc = i * 256 + lane * 4;
      float4 gv = *(const float4*)(g2 + cc);
      float4 bv = *(const float4*)(b2 + cc);
      float4 ov;
      ov.x = (xs[i*4+0] - m) * rstd * gv.x + bv.x;
      ov.y = (xs[i*4+1] - m) * rstd * gv.y + bv.y;
      ov.z = (xs[i*4+2] - m) * rstd * gv.z + bv.z;
      ov.w = (xs[i*4+3] - m) * rstd * gv.w + bv.w;
      *(float4*)(o + cc) = ov;
    }
  }
}

// ---------------- bf16 MFMA GEMM, 128x128 tile, BK=32, double-buffered LDS ----------------
__global__ __launch_bounds__(256) void k_gemm(
    const ushort_t* __restrict__ A, const ushort_t* __restrict__ Bw,
    const float* __restrict__ bias, float* __restrict__ Cout)
{
  __shared__ short As[2][128][32];
  __shared__ short Bs[2][128][32];
  int tid = threadIdx.x;
  int w = tid >> 6, lane = tid & 63;
  int row0 = blockIdx.y * 128, col0 = blockIdx.x * 128;
  int wr = (w >> 1) * 64, wc = (w & 1) * 64;
  int srow = lane >> 2;          // 0..15
  int scol = (lane & 3) * 8;     // k-elem offset
  int fr = lane & 15, kq = (lane >> 4) * 8;

  f32x4 acc[4][4];
  #pragma unroll
  for (int m = 0; m < 4; m++)
    #pragma unroll
    for (int n = 0; n < 4; n++)
      acc[m][n] = (f32x4){0.f, 0.f, 0.f, 0.f};

  // prologue: stage k-tile 0 into buffer 0
  #pragma unroll
  for (int j = 0; j < 2; j++){
    int i = 2*w + j;
    GLOAD_LDS16(A  + (size_t)(row0 + 16*i + srow) * C_ + scol, &As[0][16*i][0]);
    GLOAD_LDS16(Bw + (size_t)(col0 + 16*i + srow) * C_ + scol, &Bs[0][16*i][0]);
  }
  __syncthreads();

  int cur = 0;
  for (int kt = 0; kt < 16; kt++){
    if (kt < 15){
      int k0n = (kt + 1) * 32;
      #pragma unroll
      for (int j = 0; j < 2; j++){
        int i = 2*w + j;
        GLOAD_LDS16(A  + (size_t)(row0 + 16*i + srow) * C_ + k0n + scol, &As[cur^1][16*i][0]);
        GLOAD_LDS16(Bw + (size_t)(col0 + 16*i + srow) * C_ + k0n + scol, &Bs[cur^1][16*i][0]);
      }
    }
    bf16x8 af[4], bfr[4];
    #pragma unroll
    for (int m = 0; m < 4; m++) af[m]  = *(const bf16x8*)&As[cur][wr + m*16 + fr][kq];
    #pragma unroll
    for (int n = 0; n < 4; n++) bfr[n] = *(const bf16x8*)&Bs[cur][wc + n*16 + fr][kq];
    #pragma unroll
    for (int m = 0; m < 4; m++)
      #pragma unroll
      for (int n = 0; n < 4; n++)
        acc[m][n] = __builtin_amdgcn_mfma_f32_16x16x32_bf16(af[m], bfr[n], acc[m][n], 0, 0, 0);
    __syncthreads();     // drains this iter's staging loads (vmcnt 0) + joins
    cur ^= 1;
  }

  int cq = lane & 15, rq = (lane >> 4) * 4;
  #pragma unroll
  for (int n = 0; n < 4; n++){
    int col = col0 + wc + n*16 + cq;
    float bv = bias[col];
    #pragma unroll
    for (int m = 0; m < 4; m++){
      #pragma unroll
      for (int j = 0; j < 4; j++){
        int row = row0 + wr + m*16 + rq + j;
        Cout[(size_t)row * C_ + col] = acc[m][n][j] + bv;
      }
    }
  }
}

// ---------------- pooled + gate + merge + LN2 (wave per output row) ----------------
__global__ __launch_bounds__(256) void k_epilogue(
    const float* __restrict__ red, const ushort_t* __restrict__ pooled,
    const float* __restrict__ gw, const float* __restrict__ gbp,
    const float* __restrict__ g2, const float* __restrict__ b2,
    float* __restrict__ out, float* __restrict__ gateout)
{
  int row  = blockIdx.x * 4 + (threadIdx.x >> 6);   // b*2048 + l
  int lane = threadIdx.x & 63;
  int b = row >> 11, l = row & (LO_ - 1);
  const float* rr = red + (size_t)row * C_;
  const ushort_t* pp = pooled + (size_t)row * C_;
  float rv[8], pv[8];
  float lp = 0.f;
  #pragma unroll
  for (int i = 0; i < 2; i++){
    int c = i * 256 + lane * 4;
    float4 r4 = *(const float4*)(rr + c);
    ushort4 p4 = *(const ushort4*)(pp + c);
    float4 w1 = *(const float4*)(gw + c);
    float4 w2 = *(const float4*)(gw + C_ + c);
    float q0 = bf2f(p4.x), q1 = bf2f(p4.y), q2 = bf2f(p4.z), q3 = bf2f(p4.w);
    rv[i*4+0] = r4.x; rv[i*4+1] = r4.y; rv[i*4+2] = r4.z; rv[i*4+3] = r4.w;
    pv[i*4+0] = q0;   pv[i*4+1] = q1;   pv[i*4+2] = q2;   pv[i*4+3] = q3;
    lp += r4.x*w1.x + r4.y*w1.y + r4.z*w1.z + r4.w*w1.w
        + q0*w2.x + q1*w2.y + q2*w2.z + q3*w2.w;
  }
  lp = waveReduceSum(lp);
  float gate = 0.5f + 0.5f / (1.f + expf(-(lp + gbp[0])));
  float mv[8];
  float s1 = 0.f, s2 = 0.f;
  #pragma unroll
  for (int j = 0; j < 8; j++){
    mv[j] = pv[j] + gate * (rv[j] - pv[j]);
    s1 += mv[j]; s2 += mv[j] * mv[j];
  }
  s1 = waveReduceSum(s1); s2 = waveReduceSum(s2);
  float m = s1 * (1.f / C_);
  float rstd = rsqrtf(s2 * (1.f / C_) - m * m + 1e-5f);
  float* o = out + ((size_t)(b * LM_ + SLOTS + l)) * C_;
  #pragma unroll
  for (int i = 0; i < 2; i++){
    int c = i * 256 + lane * 4;
    float4 gv = *(const float4*)(g2 + c);
    float4 bv = *(const float4*)(b2 + c);
    float4 ov;
    ov.x = (mv[i*4+0] - m) * rstd * gv.x + bv.x;
    ov.y = (mv[i*4+1] - m) * rstd * gv.y + bv.y;
    ov.z = (mv[i*4+2] - m) * rstd * gv.z + bv.z;
    ov.w = (mv[i*4+3] - m) * rstd * gv.w + bv.w;
    *(float4*)(o + c) = ov;
  }
  if (lane == 0) gateout[b * LO_ + l] = gate;
}

extern "C" void kernel_launch(void* const* d_in, const int* in_sizes, int n_in,
                              void* d_out, int out_size, void* d_ws, size_t ws_size,
                              hipStream_t stream)
{
  const float* lat = (const float*)d_in[0];
  const float* g1  = (const float*)d_in[1];
  const float* b1  = (const float*)d_in[2];
  const float* dw  = (const float*)d_in[3];
  const float* db  = (const float*)d_in[4];
  const float* pw  = (const float*)d_in[5];
  const float* pb  = (const float*)d_in[6];
  const float* gw  = (const float*)d_in[7];
  const float* gb  = (const float*)d_in[8];
  const float* cw  = (const float*)d_in[9];
  const float* cb  = (const float*)d_in[10];
  const float* g2  = (const float*)d_in[11];
  const float* b2  = (const float*)d_in[12];

  float* out = (float*)d_out;
  float* gateout = out + (size_t)B_ * LM_ * C_;

  const size_t NHL = (size_t)B_ * LO_ * C_;   // 8388608
  ushort_t* hbuf   = (ushort_t*)d_ws;
  ushort_t* pooled = hbuf + NHL;
  float*    red    = (float*)(pooled + NHL);
  ushort_t* pwb    = (ushort_t*)(red + NHL);
  float*    scores = (float*)(pwb + (size_t)C_ * C_);
  float*    cand_v = scores + (size_t)B_ * L_;
  int*      cand_i = (int*)(cand_v + B_ * 64);

  hipLaunchKernelGGL(k_cast,    dim3(C_ * C_ / 1024), dim3(256), 0, stream, pw, pwb);
  hipLaunchKernelGGL(k_conv,    dim3(B_ * LO_ / 4), dim3(256), 0, stream,
                     lat, g1, b1, dw, db, cw, cb, hbuf, pooled, scores);
  hipLaunchKernelGGL(k_topk1,   dim3(B_ * 8), dim3(256), 0, stream, scores, cand_v, cand_i);
  hipLaunchKernelGGL(k_topk2,   dim3(B_), dim3(256), 0, stream, cand_v, cand_i, lat, g2, b2, out);
  hipLaunchKernelGGL(k_gemm,    dim3(C_ / 128, B_ * LO_ / 128), dim3(256), 0, stream, hbuf, pwb, pb, red);
  hipLaunchKernelGGL(k_epilogue,dim3(B_ * LO_ / 4), dim3(256), 0, stream, red, pooled, gw, gb, g2, b2, out, gateout);
}

// Round 4
// 77.167 us; speedup vs baseline: 2.7355x; 1.2329x over previous
//
#include <hip/hip_runtime.h>
#include <hip/hip_bf16.h>
#include <math.h>

#define B_ 8
#define L_ 4096
#define C_ 512
#define LO_ 2048   // L/2
#define SLOTS 8
#define LM_ 2056   // SLOTS + LO_

typedef __attribute__((ext_vector_type(8))) short bf16x8;
typedef __attribute__((ext_vector_type(4))) float f32x4;
typedef unsigned short ushort_t;

__device__ __forceinline__ float waveReduceSum(float v){
  #pragma unroll
  for (int off = 32; off; off >>= 1) v += __shfl_xor(v, off);
  return v;
}

__device__ __forceinline__ unsigned short f2bf(float f){
  unsigned u = __float_as_uint(f);
  u += 0x7fffu + ((u >> 16) & 1u);   // RNE
  return (unsigned short)(u >> 16);
}
__device__ __forceinline__ float bf2f(unsigned short b){
  return __uint_as_float(((unsigned)b) << 16);
}

#define GLOAD_LDS16(g, l) __builtin_amdgcn_global_load_lds( \
    (__attribute__((address_space(1))) void*)(g), \
    (__attribute__((address_space(3))) void*)(l), 16, 0, 0)

// ---------------- pw_w fp32 -> bf16 ----------------
__global__ __launch_bounds__(256) void k_cast(const float* __restrict__ src, ushort_t* __restrict__ dst){
  int i = (blockIdx.x * 256 + threadIdx.x) * 4;
  float4 v = *(const float4*)(src + i);
  ushort4 o;
  o.x = f2bf(v.x); o.y = f2bf(v.y); o.z = f2bf(v.z); o.w = f2bf(v.w);
  *(ushort4*)(dst + i) = o;
}

// ---------------- fused: LN1 + carrier score + depthwise conv + GELU + pooled ----------------
// Phase 1: wave-per-row stats (rows staged to LDS); Phase 2: channel-major conv from LDS.
// Block covers 4 outputs = rows lbase..lbase+8 (lbase = 8*chunk-1).
__global__ __launch_bounds__(256) void k_conv(
    const float* __restrict__ lat, const float* __restrict__ g1, const float* __restrict__ b1,
    const float* __restrict__ dw, const float* __restrict__ db,
    const float* __restrict__ cw, const float* __restrict__ cbp,
    ushort_t* __restrict__ hbuf, ushort_t* __restrict__ pooled, float* __restrict__ scores)
{
  __shared__ float rows[9][C_];    // 18 KB
  __shared__ float stat[9][3];     // m, rstd, sd
  __shared__ float sc_[2];         // sgc, sbc
  int blk = blockIdx.x;            // b * 512 + chunk
  int b = blk >> 9;
  int chunk = blk & 511;
  int t0 = chunk * 4;
  int tid = threadIdx.x;
  int wv = tid >> 6, lane = tid & 63;
  int lbase = 8 * chunk - 1;       // in-batch row index of r=0 (may be -1)

  // channel slice for this lane (phase 1): [lane*4, lane*4+3] and +256
  int c4 = lane * 4;
  float4 glo = *(const float4*)(g1 + c4);
  float4 ghi = *(const float4*)(g1 + 256 + c4);
  float4 wlo = *(const float4*)(cw + c4);
  float4 whi = *(const float4*)(cw + 256 + c4);
  float4 gclo, gchi;
  gclo.x = glo.x*wlo.x; gclo.y = glo.y*wlo.y; gclo.z = glo.z*wlo.z; gclo.w = glo.w*wlo.w;
  gchi.x = ghi.x*whi.x; gchi.y = ghi.y*whi.y; gchi.z = ghi.z*whi.z; gchi.w = ghi.w*whi.w;

  if (wv == 3){
    float4 blo = *(const float4*)(b1 + c4);
    float4 bhi = *(const float4*)(b1 + 256 + c4);
    float sgc = gclo.x+gclo.y+gclo.z+gclo.w + gchi.x+gchi.y+gchi.z+gchi.w;
    float sbc = blo.x*wlo.x + blo.y*wlo.y + blo.z*wlo.z + blo.w*wlo.w
              + bhi.x*whi.x + bhi.y*whi.y + bhi.z*whi.z + bhi.w*whi.w;
    sgc = waveReduceSum(sgc);
    sbc = waveReduceSum(sbc);
    if (lane == 0){ sc_[0] = sgc; sc_[1] = sbc; }
  }

  // phase 1: wave wv handles rows wv, wv+4, wv+8
  for (int r = wv; r < 9; r += 4){
    int l = lbase + r;
    float4 v0, v1;
    if (l >= 0){
      const float* xp = lat + ((size_t)(b * L_ + l)) * C_;
      v0 = *(const float4*)(xp + c4);
      v1 = *(const float4*)(xp + 256 + c4);
    } else {
      v0.x=0.f; v0.y=0.f; v0.z=0.f; v0.w=0.f;
      v1 = v0;
    }
    *(float4*)&rows[r][c4] = v0;
    *(float4*)&rows[r][256 + c4] = v1;
    float s1 = v0.x+v0.y+v0.z+v0.w + v1.x+v1.y+v1.z+v1.w;
    float s2 = v0.x*v0.x+v0.y*v0.y+v0.z*v0.z+v0.w*v0.w
             + v1.x*v1.x+v1.y*v1.y+v1.z*v1.z+v1.w*v1.w;
    float sd = v0.x*gclo.x+v0.y*gclo.y+v0.z*gclo.z+v0.w*gclo.w
             + v1.x*gchi.x+v1.y*gchi.y+v1.z*gchi.z+v1.w*gchi.w;
    s1 = waveReduceSum(s1);
    s2 = waveReduceSum(s2);
    sd = waveReduceSum(sd);
    if (lane == 0){
      float m = s1 * (1.f / C_);
      float var = s2 * (1.f / C_) - m * m;
      stat[r][0] = m;
      stat[r][1] = rsqrtf(var + 1e-5f);
      stat[r][2] = sd;
    }
  }
  __syncthreads();

  // scores for rows r=1..8 (each global row scored by exactly one block)
  if (tid >= 1 && tid <= 8){
    int r = tid;
    float sc = (stat[r][2] - stat[r][0] * sc_[0]) * stat[r][1] + sc_[1] + cbp[0];
    scores[b * L_ + lbase + r] = sc;
  }

  // phase 2: channel-major conv, 2 channels per thread, from LDS
  int c = tid * 2;
  float g0 = g1[c], g1v = g1[c+1];
  float bb0 = b1[c], bb1 = b1[c+1];
  float w00 = dw[c*3+0], w01 = dw[c*3+1], w02 = dw[c*3+2];
  float w10 = dw[(c+1)*3+0], w11 = dw[(c+1)*3+1], w12 = dw[(c+1)*3+2];
  float db0 = db[c], db1 = db[c+1];
  float2 xr[9]; float mr[9], rr[9];
  #pragma unroll
  for (int r = 0; r < 9; r++){
    xr[r] = *(const float2*)&rows[r][c];
    mr[r] = stat[r][0]; rr[r] = stat[r][1];
  }
  bool pad0 = (chunk == 0);
  #pragma unroll
  for (int t = 0; t < 4; t++){
    int rl = 2*t, rm = 2*t+1, rrg = 2*t+2;
    float n0x, n0y;
    if (pad0 && t == 0){ n0x = 0.f; n0y = 0.f; }
    else {
      n0x = (xr[rl].x - mr[rl]) * rr[rl] * g0 + bb0;
      n0y = (xr[rl].y - mr[rl]) * rr[rl] * g1v + bb1;
    }
    float n1x = (xr[rm].x - mr[rm]) * rr[rm] * g0 + bb0;
    float n1y = (xr[rm].y - mr[rm]) * rr[rm] * g1v + bb1;
    float n2x = (xr[rrg].x - mr[rrg]) * rr[rrg] * g0 + bb0;
    float n2y = (xr[rrg].y - mr[rrg]) * rr[rrg] * g1v + bb1;
    float h0 = n0x * w00 + n1x * w01 + n2x * w02 + db0;
    float h1 = n0y * w10 + n1y * w11 + n2y * w12 + db1;
    float ge0 = 0.5f * h0 * (1.f + erff(h0 * 0.70710678118654752440f));
    float ge1 = 0.5f * h1 * (1.f + erff(h1 * 0.70710678118654752440f));
    size_t oidx = ((size_t)(b * LO_ + t0 + t)) * C_ + c;
    ushort2 hv; hv.x = f2bf(ge0); hv.y = f2bf(ge1);
    *(ushort2*)(hbuf + oidx) = hv;
    float p0 = 0.5f * (xr[rm].x + xr[rrg].x);
    float p1 = 0.5f * (xr[rm].y + xr[rrg].y);
    ushort2 pv; pv.x = f2bf(p0); pv.y = f2bf(p1);
    *(ushort2*)(pooled + oidx) = pv;
  }
}

// ---------------- top-k stage 1: top-8 of each 512-chunk (64 blocks) ----------------
__global__ __launch_bounds__(256) void k_topk1(
    const float* __restrict__ scores, float* __restrict__ cand_v, int* __restrict__ cand_i)
{
  __shared__ float sv[512];
  __shared__ float rv_[4];
  __shared__ int   ri_[4];
  int blk = blockIdx.x;          // b*8 + chunk
  int base = blk * 512;
  int tid = threadIdx.x;
  sv[tid] = scores[base + tid];
  sv[tid + 256] = scores[base + tid + 256];
  __syncthreads();
  int wv = tid >> 6, lane = tid & 63;
  for (int it = 0; it < SLOTS; it++){
    float v0 = sv[tid], v1 = sv[tid + 256];
    float best; int bi;
    if (v0 >= v1){ best = v0; bi = tid; } else { best = v1; bi = tid + 256; }
    #pragma unroll
    for (int off = 32; off; off >>= 1){
      float ov = __shfl_xor(best, off); int oi = __shfl_xor(bi, off);
      if (ov > best || (ov == best && oi < bi)){ best = ov; bi = oi; }
    }
    if (lane == 0){ rv_[wv] = best; ri_[wv] = bi; }
    __syncthreads();
    if (tid == 0){
      for (int w2 = 1; w2 < 4; w2++){
        if (rv_[w2] > best || (rv_[w2] == best && ri_[w2] < bi)){ best = rv_[w2]; bi = ri_[w2]; }
      }
      cand_v[blk * 8 + it] = best;
      cand_i[blk * 8 + it] = base + bi;
      sv[bi] = -INFINITY;
    }
    __syncthreads();
  }
}

// ---------------- top-k stage 2 (select 8 of 64) + carrier gather + LN2 ----------------
__global__ __launch_bounds__(256) void k_topk2(
    const float* __restrict__ cand_v, const int* __restrict__ cand_i,
    const float* __restrict__ lat,
    const float* __restrict__ g2, const float* __restrict__ b2, float* __restrict__ out)
{
  __shared__ int chosen[SLOTS];
  int b = blockIdx.x, tid = threadIdx.x;
  if (tid < 64){
    float v = cand_v[b * 64 + tid];
    int  idx = cand_i[b * 64 + tid];
    for (int it = 0; it < SLOTS; it++){
      float best = v; int bi = idx;
      #pragma unroll
      for (int off = 32; off; off >>= 1){
        float ov = __shfl_xor(best, off); int oi = __shfl_xor(bi, off);
        if (ov > best || (ov == best && oi < bi)){ best = ov; bi = oi; }
      }
      if (tid == 0) chosen[it] = bi;
      if (idx == bi) v = -INFINITY;
    }
  }
  __syncthreads();
  if (tid == 0){
    for (int i = 0; i < SLOTS; i++)
      for (int j = i + 1; j < SLOTS; j++)
        if (chosen[j] < chosen[i]){ int t = chosen[i]; chosen[i] = chosen[j]; chosen[j] = t; }
  }
  __syncthreads();
  int wv = tid >> 6, lane = tid & 63;
  for (int s = wv; s < SLOTS; s += 4){
    int l = chosen[s] - b * L_;
    const float* x = lat + ((size_t)(b * L_ + l)) * C_;
    float xs[8];
    float s1 = 0.f, s2 = 0.f;
    #pragma unroll
    for (int i = 0; i < 2; i++){
      float4 vv = *(const float4*)(x + i * 256 + lane * 4);
      xs[i*4+0] = vv.x; xs[i*4+1] = vv.y; xs[i*4+2] = vv.z; xs[i*4+3] = vv.w;
      s1 += vv.x + vv.y + vv.z + vv.w;
      s2 += vv.x*vv.x + vv.y*vv.y + vv.z*vv.z + vv.w*vv.w;
    }
    s1 = waveReduceSum(s1); s2 = waveReduceSum(s2);
    float m = s1 * (1.f / C_);
    float rstd = rsqrtf(s2 * (1.f / C_) - m * m + 1e-5f);
    float* o = out + ((size_t)(b * LM_ + s)) * C_;
    #pragma unroll
    for (int i = 0; i < 2; i++){
      int cc = i * 256 + lane * 4;
      float4 gv = *(const float4*)(g2 + cc);
      float4 bv = *(const float4*)(b2 + cc);
      float4 ov;
      ov.x = (xs[i*4+0] - m) * rstd * gv.x + bv.x;
      ov.y = (xs[i*4+1] - m) * rstd * gv.y + bv.y;
      ov.z = (xs[i*4+2] - m) * rstd * gv.z + bv.z;
      ov.w = (xs[i*4+3] - m) * rstd * gv.w + bv.w;
      *(float4*)(o + cc) = ov;
    }
  }
}

// ---------------- bf16 MFMA GEMM, 128x128 tile, BK=32, double-buffered, bf16 out ----------------
__global__ __launch_bounds__(256) void k_gemm(
    const ushort_t* __restrict__ A, const ushort_t* __restrict__ Bw,
    const float* __restrict__ bias, ushort_t* __restrict__ Cout)
{
  __shared__ short As[2][128][32];
  __shared__ short Bs[2][128][32];
  int tid = threadIdx.x;
  int w = tid >> 6, lane = tid & 63;
  int row0 = blockIdx.y * 128, col0 = blockIdx.x * 128;
  int wr = (w >> 1) * 64, wc = (w & 1) * 64;
  int srow = lane >> 2;
  int scol = (lane & 3) * 8;
  int fr = lane & 15, kq = (lane >> 4) * 8;

  f32x4 acc[4][4];
  #pragma unroll
  for (int m = 0; m < 4; m++)
    #pragma unroll
    for (int n = 0; n < 4; n++)
      acc[m][n] = (f32x4){0.f, 0.f, 0.f, 0.f};

  #pragma unroll
  for (int j = 0; j < 2; j++){
    int i = 2*w + j;
    GLOAD_LDS16(A  + (size_t)(row0 + 16*i + srow) * C_ + scol, &As[0][16*i][0]);
    GLOAD_LDS16(Bw + (size_t)(col0 + 16*i + srow) * C_ + scol, &Bs[0][16*i][0]);
  }
  __syncthreads();

  int cur = 0;
  for (int kt = 0; kt < 16; kt++){
    if (kt < 15){
      int k0n = (kt + 1) * 32;
      #pragma unroll
      for (int j = 0; j < 2; j++){
        int i = 2*w + j;
        GLOAD_LDS16(A  + (size_t)(row0 + 16*i + srow) * C_ + k0n + scol, &As[cur^1][16*i][0]);
        GLOAD_LDS16(Bw + (size_t)(col0 + 16*i + srow) * C_ + k0n + scol, &Bs[cur^1][16*i][0]);
      }
    }
    bf16x8 af[4], bfr[4];
    #pragma unroll
    for (int m = 0; m < 4; m++) af[m]  = *(const bf16x8*)&As[cur][wr + m*16 + fr][kq];
    #pragma unroll
    for (int n = 0; n < 4; n++) bfr[n] = *(const bf16x8*)&Bs[cur][wc + n*16 + fr][kq];
    #pragma unroll
    for (int m = 0; m < 4; m++)
      #pragma unroll
      for (int n = 0; n < 4; n++)
        acc[m][n] = __builtin_amdgcn_mfma_f32_16x16x32_bf16(af[m], bfr[n], acc[m][n], 0, 0, 0);
    __syncthreads();
    cur ^= 1;
  }

  int cq = lane & 15, rq = (lane >> 4) * 4;
  #pragma unroll
  for (int n = 0; n < 4; n++){
    int col = col0 + wc + n*16 + cq;
    float bv = bias[col];
    #pragma unroll
    for (int m = 0; m < 4; m++){
      #pragma unroll
      for (int j = 0; j < 4; j++){
        int row = row0 + wr + m*16 + rq + j;
        Cout[(size_t)row * C_ + col] = f2bf(acc[m][n][j] + bv);
      }
    }
  }
}

// ---------------- pooled + gate + merge + LN2 (wave per output row) ----------------
__global__ __launch_bounds__(256) void k_epilogue(
    const ushort_t* __restrict__ red, const ushort_t* __restrict__ pooled,
    const float* __restrict__ gw, const float* __restrict__ gbp,
    const float* __restrict__ g2, const float* __restrict__ b2,
    float* __restrict__ out, float* __restrict__ gateout)
{
  int row  = blockIdx.x * 4 + (threadIdx.x >> 6);   // b*2048 + l
  int lane = threadIdx.x & 63;
  int b = row >> 11, l = row & (LO_ - 1);
  const ushort_t* rr = red + (size_t)row * C_;
  const ushort_t* pp = pooled + (size_t)row * C_;
  float rv[8], pv[8];
  float lp = 0.f;
  #pragma unroll
  for (int i = 0; i < 2; i++){
    int c = i * 256 + lane * 4;
    ushort4 r4 = *(const ushort4*)(rr + c);
    ushort4 p4 = *(const ushort4*)(pp + c);
    float4 w1 = *(const float4*)(gw + c);
    float4 w2 = *(const float4*)(gw + C_ + c);
    float r0 = bf2f(r4.x), r1 = bf2f(r4.y), r2 = bf2f(r4.z), r3 = bf2f(r4.w);
    float q0 = bf2f(p4.x), q1 = bf2f(p4.y), q2 = bf2f(p4.z), q3 = bf2f(p4.w);
    rv[i*4+0] = r0; rv[i*4+1] = r1; rv[i*4+2] = r2; rv[i*4+3] = r3;
    pv[i*4+0] = q0; pv[i*4+1] = q1; pv[i*4+2] = q2; pv[i*4+3] = q3;
    lp += r0*w1.x + r1*w1.y + r2*w1.z + r3*w1.w
        + q0*w2.x + q1*w2.y + q2*w2.z + q3*w2.w;
  }
  lp = waveReduceSum(lp);
  float gate = 0.5f + 0.5f / (1.f + expf(-(lp + gbp[0])));
  float mv[8];
  float s1 = 0.f, s2 = 0.f;
  #pragma unroll
  for (int j = 0; j < 8; j++){
    mv[j] = pv[j] + gate * (rv[j] - pv[j]);
    s1 += mv[j]; s2 += mv[j] * mv[j];
  }
  s1 = waveReduceSum(s1); s2 = waveReduceSum(s2);
  float m = s1 * (1.f / C_);
  float rstd = rsqrtf(s2 * (1.f / C_) - m * m + 1e-5f);
  float* o = out + ((size_t)(b * LM_ + SLOTS + l)) * C_;
  #pragma unroll
  for (int i = 0; i < 2; i++){
    int c = i * 256 + lane * 4;
    float4 gv = *(const float4*)(g2 + c);
    float4 bv = *(const float4*)(b2 + c);
    float4 ov;
    ov.x = (mv[i*4+0] - m) * rstd * gv.x + bv.x;
    ov.y = (mv[i*4+1] - m) * rstd * gv.y + bv.y;
    ov.z = (mv[i*4+2] - m) * rstd * gv.z + bv.z;
    ov.w = (mv[i*4+3] - m) * rstd * gv.w + bv.w;
    *(float4*)(o + c) = ov;
  }
  if (lane == 0) gateout[b * LO_ + l] = gate;
}

extern "C" void kernel_launch(void* const* d_in, const int* in_sizes, int n_in,
                              void* d_out, int out_size, void* d_ws, size_t ws_size,
                              hipStream_t stream)
{
  const float* lat = (const float*)d_in[0];
  const float* g1  = (const float*)d_in[1];
  const float* b1  = (const float*)d_in[2];
  const float* dw  = (const float*)d_in[3];
  const float* db  = (const float*)d_in[4];
  const float* pw  = (const float*)d_in[5];
  const float* pb  = (const float*)d_in[6];
  const float* gw  = (const float*)d_in[7];
  const float* gb  = (const float*)d_in[8];
  const float* cw  = (const float*)d_in[9];
  const float* cb  = (const float*)d_in[10];
  const float* g2  = (const float*)d_in[11];
  const float* b2  = (const float*)d_in[12];

  float* out = (float*)d_out;
  float* gateout = out + (size_t)B_ * LM_ * C_;

  const size_t NHL = (size_t)B_ * LO_ * C_;   // 8388608
  ushort_t* hbuf   = (ushort_t*)d_ws;
  ushort_t* pooled = hbuf + NHL;
  ushort_t* redb   = pooled + NHL;
  ushort_t* pwb    = redb + NHL;
  float*    scores = (float*)(pwb + (size_t)C_ * C_);
  float*    cand_v = scores + (size_t)B_ * L_;
  int*      cand_i = (int*)(cand_v + B_ * 64);

  hipLaunchKernelGGL(k_cast,    dim3(C_ * C_ / 1024), dim3(256), 0, stream, pw, pwb);
  hipLaunchKernelGGL(k_conv,    dim3(B_ * LO_ / 4), dim3(256), 0, stream,
                     lat, g1, b1, dw, db, cw, cb, hbuf, pooled, scores);
  hipLaunchKernelGGL(k_topk1,   dim3(B_ * 8), dim3(256), 0, stream, scores, cand_v, cand_i);
  hipLaunchKernelGGL(k_topk2,   dim3(B_), dim3(256), 0, stream, cand_v, cand_i, lat, g2, b2, out);
  hipLaunchKernelGGL(k_gemm,    dim3(C_ / 128, B_ * LO_ / 128), dim3(256), 0, stream, hbuf, pwb, pb, redb);
  hipLaunchKernelGGL(k_epilogue,dim3(B_ * LO_ / 4), dim3(256), 0, stream, redb, pooled, gw, gb, g2, b2, out, gateout);
}

// Round 5
// 75.959 us; speedup vs baseline: 2.7790x; 1.0159x over previous
//
#include <hip/hip_runtime.h>
#include <hip/hip_bf16.h>
#include <math.h>

#define B_ 8
#define L_ 4096
#define C_ 512
#define LO_ 2048   // L/2
#define SLOTS 8
#define LM_ 2056   // SLOTS + LO_

typedef __attribute__((ext_vector_type(8))) short bf16x8;
typedef __attribute__((ext_vector_type(4))) float f32x4;
typedef unsigned short ushort_t;

__device__ __forceinline__ float waveReduceSum(float v){
  #pragma unroll
  for (int off = 32; off; off >>= 1) v += __shfl_xor(v, off);
  return v;
}

__device__ __forceinline__ unsigned short f2bf(float f){
  unsigned u = __float_as_uint(f);
  u += 0x7fffu + ((u >> 16) & 1u);   // RNE
  return (unsigned short)(u >> 16);
}
__device__ __forceinline__ float bf2f(unsigned short b){
  return __uint_as_float(((unsigned)b) << 16);
}

#define GLOAD_LDS16(g, l) __builtin_amdgcn_global_load_lds( \
    (__attribute__((address_space(1))) void*)(g), \
    (__attribute__((address_space(3))) void*)(l), 16, 0, 0)

// ---------------- fused: [pw cast] + LN1 + carrier score + depthwise conv + GELU + pooled ----
// 2048 blocks x 512 threads; block = 8 outputs (17 source rows).
// Phase 1: wave-per-row stats, rows staged to LDS. Phase 2: 4-channel-quad conv from LDS.
__global__ __launch_bounds__(512) void k_conv(
    const float* __restrict__ lat, const float* __restrict__ g1, const float* __restrict__ b1,
    const float* __restrict__ dw, const float* __restrict__ db,
    const float* __restrict__ cw, const float* __restrict__ cbp,
    const float* __restrict__ pw, ushort_t* __restrict__ pwb,
    ushort_t* __restrict__ hbuf, ushort_t* __restrict__ pooled, float* __restrict__ scores)
{
  __shared__ float rows[17][C_];   // 34 KB
  __shared__ float stat[17][3];    // m, rstd, sd
  __shared__ float sc_[2];         // sgc, sbc
  int blk = blockIdx.x;            // b * 256 + chunk
  int b = blk >> 8;
  int chunk = blk & 255;
  int t0 = chunk * 8;
  int tid = threadIdx.x;
  int wv = tid >> 6, lane = tid & 63;
  int lbase = 16 * chunk - 1;      // in-batch row of r=0 (may be -1)

  // fold-in: cast pw fp32 -> bf16 (blocks 0..255 cover 512*512 elems)
  if (blk < 256){
    int i = blk * 1024 + tid * 2;
    float2 v = *(const float2*)(pw + i);
    ushort2 o; o.x = f2bf(v.x); o.y = f2bf(v.y);
    *(ushort2*)(pwb + i) = o;
  }

  int c4 = lane * 4;
  float4 glo = *(const float4*)(g1 + c4);
  float4 ghi = *(const float4*)(g1 + 256 + c4);
  float4 wlo = *(const float4*)(cw + c4);
  float4 whi = *(const float4*)(cw + 256 + c4);
  float4 gclo, gchi;
  gclo.x = glo.x*wlo.x; gclo.y = glo.y*wlo.y; gclo.z = glo.z*wlo.z; gclo.w = glo.w*wlo.w;
  gchi.x = ghi.x*whi.x; gchi.y = ghi.y*whi.y; gchi.z = ghi.z*whi.z; gchi.w = ghi.w*whi.w;

  if (wv == 7){
    float4 blo = *(const float4*)(b1 + c4);
    float4 bhi = *(const float4*)(b1 + 256 + c4);
    float sgc = gclo.x+gclo.y+gclo.z+gclo.w + gchi.x+gchi.y+gchi.z+gchi.w;
    float sbc = blo.x*wlo.x + blo.y*wlo.y + blo.z*wlo.z + blo.w*wlo.w
              + bhi.x*whi.x + bhi.y*whi.y + bhi.z*whi.z + bhi.w*whi.w;
    sgc = waveReduceSum(sgc);
    sbc = waveReduceSum(sbc);
    if (lane == 0){ sc_[0] = sgc; sc_[1] = sbc; }
  }

  // phase 1: wave wv handles rows wv, wv+8, (wv+16 if wv==0)
  for (int r = wv; r < 17; r += 8){
    int l = lbase + r;
    float4 v0, v1;
    if (l >= 0){
      const float* xp = lat + ((size_t)(b * L_ + l)) * C_;
      v0 = *(const float4*)(xp + c4);
      v1 = *(const float4*)(xp + 256 + c4);
    } else {
      v0.x=0.f; v0.y=0.f; v0.z=0.f; v0.w=0.f;
      v1 = v0;
    }
    *(float4*)&rows[r][c4] = v0;
    *(float4*)&rows[r][256 + c4] = v1;
    float s1 = v0.x+v0.y+v0.z+v0.w + v1.x+v1.y+v1.z+v1.w;
    float s2 = v0.x*v0.x+v0.y*v0.y+v0.z*v0.z+v0.w*v0.w
             + v1.x*v1.x+v1.y*v1.y+v1.z*v1.z+v1.w*v1.w;
    float sd = v0.x*gclo.x+v0.y*gclo.y+v0.z*gclo.z+v0.w*gclo.w
             + v1.x*gchi.x+v1.y*gchi.y+v1.z*gchi.z+v1.w*gchi.w;
    s1 = waveReduceSum(s1);
    s2 = waveReduceSum(s2);
    sd = waveReduceSum(sd);
    if (lane == 0){
      float m = s1 * (1.f / C_);
      float var = s2 * (1.f / C_) - m * m;
      stat[r][0] = m;
      stat[r][1] = rsqrtf(var + 1e-5f);
      stat[r][2] = sd;
    }
  }
  __syncthreads();

  // scores for rows r=1..16 (each global row scored by exactly one block)
  if (tid >= 1 && tid <= 16){
    int r = tid;
    float sc = (stat[r][2] - stat[r][0] * sc_[0]) * stat[r][1] + sc_[1] + cbp[0];
    scores[b * L_ + lbase + r] = sc;
  }

  // phase 2: thread = (th, cq): th = tid>>7 in 0..3 -> outputs {2th, 2th+1};
  //          cq = (tid&127)*4 -> 4 channels
  int th = tid >> 7;
  int cq = (tid & 127) * 4;
  float4 gq = *(const float4*)(g1 + cq);
  float4 bq = *(const float4*)(b1 + cq);
  float4 dbq = *(const float4*)(db + cq);
  float4 w0 = *(const float4*)(dw + cq*3);        // ch cq: k0,k1,k2 ; ch cq+1: k0
  float4 w1 = *(const float4*)(dw + cq*3 + 4);    // ch cq+1: k1,k2 ; ch cq+2: k0,k1
  float4 w2 = *(const float4*)(dw + cq*3 + 8);    // ch cq+2: k2 ; ch cq+3: k0,k1,k2
  float wk[4][3] = {{w0.x, w0.y, w0.z}, {w0.w, w1.x, w1.y},
                    {w1.z, w1.w, w2.x}, {w2.y, w2.z, w2.w}};
  float gk[4] = {gq.x, gq.y, gq.z, gq.w};
  float bk[4] = {bq.x, bq.y, bq.z, bq.w};
  float dbk[4] = {dbq.x, dbq.y, dbq.z, dbq.w};
  #pragma unroll
  for (int i = 0; i < 2; i++){
    int t = th * 2 + i;                // local output 0..7
    int rl = 2*t, rm = 2*t+1, rrg = 2*t+2;
    float4 xl = *(const float4*)&rows[rl][cq];
    float4 xm = *(const float4*)&rows[rm][cq];
    float4 xrr = *(const float4*)&rows[rrg][cq];
    float ml = stat[rl][0], rlr = stat[rl][1];
    float mm = stat[rm][0], rmr = stat[rm][1];
    float mr2 = stat[rrg][0], rrr = stat[rrg][1];
    bool zpad = (chunk == 0 && t == 0);
    float xlv[4] = {xl.x, xl.y, xl.z, xl.w};
    float xmv[4] = {xm.x, xm.y, xm.z, xm.w};
    float xrv[4] = {xrr.x, xrr.y, xrr.z, xrr.w};
    ushort4 hv, pv;
    unsigned short* hp = (unsigned short*)&hv;
    unsigned short* pp = (unsigned short*)&pv;
    #pragma unroll
    for (int k = 0; k < 4; k++){
      float n0 = zpad ? 0.f : ((xlv[k] - ml) * rlr * gk[k] + bk[k]);
      float n1 = (xmv[k] - mm) * rmr * gk[k] + bk[k];
      float n2 = (xrv[k] - mr2) * rrr * gk[k] + bk[k];
      float hh = n0 * wk[k][0] + n1 * wk[k][1] + n2 * wk[k][2] + dbk[k];
      float ge = 0.5f * hh * (1.f + erff(hh * 0.70710678118654752440f));
      hp[k] = f2bf(ge);
      pp[k] = f2bf(0.5f * (xmv[k] + xrv[k]));
    }
    size_t oidx = ((size_t)(b * LO_ + t0 + t)) * C_ + cq;
    *(ushort4*)(hbuf + oidx) = hv;
    *(ushort4*)(pooled + oidx) = pv;
  }
}

// ---------------- top-8 (block per batch) + carrier gather + LN2 ----------------
__global__ __launch_bounds__(1024) void k_topk(
    const float* __restrict__ scores, const float* __restrict__ lat,
    const float* __restrict__ g2, const float* __restrict__ b2, float* __restrict__ out)
{
  __shared__ float sv[L_];         // 16 KB
  __shared__ float rv_[16];
  __shared__ int   ri_[16];
  __shared__ int   chosen[SLOTS];
  int b = blockIdx.x, tid = threadIdx.x;
  #pragma unroll
  for (int j = 0; j < 4; j++) sv[tid + j * 1024] = scores[b * L_ + tid + j * 1024];
  __syncthreads();
  int wv = tid >> 6, lane = tid & 63;
  for (int it = 0; it < SLOTS; it++){
    float best = -INFINITY; int bi = L_;
    #pragma unroll
    for (int j = 0; j < 4; j++){
      int i = tid + j * 1024;
      float v = sv[i];
      if (v > best || (v == best && i < bi)){ best = v; bi = i; }
    }
    #pragma unroll
    for (int off = 32; off; off >>= 1){
      float ov = __shfl_xor(best, off); int oi = __shfl_xor(bi, off);
      if (ov > best || (ov == best && oi < bi)){ best = ov; bi = oi; }
    }
    if (lane == 0){ rv_[wv] = best; ri_[wv] = bi; }
    __syncthreads();
    if (tid == 0){
      for (int w2 = 1; w2 < 16; w2++){
        if (rv_[w2] > best || (rv_[w2] == best && ri_[w2] < bi)){ best = rv_[w2]; bi = ri_[w2]; }
      }
      chosen[it] = bi;
      sv[bi] = -INFINITY;
    }
    __syncthreads();
  }
  if (tid == 0){
    for (int i = 0; i < SLOTS; i++)
      for (int j = i + 1; j < SLOTS; j++)
        if (chosen[j] < chosen[i]){ int t = chosen[i]; chosen[i] = chosen[j]; chosen[j] = t; }
  }
  __syncthreads();
  if (wv < SLOTS){
    int s = wv;
    int l = chosen[s];
    const float* x = lat + ((size_t)(b * L_ + l)) * C_;
    float xs[8];
    float s1 = 0.f, s2 = 0.f;
    #pragma unroll
    for (int i = 0; i < 2; i++){
      float4 vv = *(const float4*)(x + i * 256 + lane * 4);
      xs[i*4+0] = vv.x; xs[i*4+1] = vv.y; xs[i*4+2] = vv.z; xs[i*4+3] = vv.w;
      s1 += vv.x + vv.y + vv.z + vv.w;
      s2 += vv.x*vv.x + vv.y*vv.y + vv.z*vv.z + vv.w*vv.w;
    }
    s1 = waveReduceSum(s1); s2 = waveReduceSum(s2);
    float m = s1 * (1.f / C_);
    float rstd = rsqrtf(s2 * (1.f / C_) - m * m + 1e-5f);
    float* o = out + ((size_t)(b * LM_ + s)) * C_;
    #pragma unroll
    for (int i = 0; i < 2; i++){
      int cc = i * 256 + lane * 4;
      float4 gv = *(const float4*)(g2 + cc);
      float4 bv = *(const float4*)(b2 + cc);
      float4 ov;
      ov.x = (xs[i*4+0] - m) * rstd * gv.x + bv.x;
      ov.y = (xs[i*4+1] - m) * rstd * gv.y + bv.y;
      ov.z = (xs[i*4+2] - m) * rstd * gv.z + bv.z;
      ov.w = (xs[i*4+3] - m) * rstd * gv.w + bv.w;
      *(float4*)(o + cc) = ov;
    }
  }
}

// ---------------- bf16 MFMA GEMM, 128x128 tile, BK=32, dbuf, XCD-swizzled, bf16 out ----------
__global__ __launch_bounds__(256) void k_gemm(
    const ushort_t* __restrict__ A, const ushort_t* __restrict__ Bw,
    const float* __restrict__ bias, ushort_t* __restrict__ Cout)
{
  __shared__ short As[2][128][32];
  __shared__ short Bs[2][128][32];
  int tid = threadIdx.x;
  int w = tid >> 6, lane = tid & 63;
  // XCD-aware swizzle: nwg=512, 8 XCDs -> XCD k owns tiles [k*64, k*64+64):
  // 16 consecutive row-panels with their 4 col-tiles -> A panel L2-resident per XCD.
  int hw = blockIdx.y * 4 + blockIdx.x;
  int tile = ((hw & 7) << 6) | (hw >> 3);
  int row0 = (tile >> 2) * 128, col0 = (tile & 3) * 128;
  int wr = (w >> 1) * 64, wc = (w & 1) * 64;
  int srow = lane >> 2;
  int scol = (lane & 3) * 8;
  int fr = lane & 15, kq = (lane >> 4) * 8;

  f32x4 acc[4][4];
  #pragma unroll
  for (int m = 0; m < 4; m++)
    #pragma unroll
    for (int n = 0; n < 4; n++)
      acc[m][n] = (f32x4){0.f, 0.f, 0.f, 0.f};

  #pragma unroll
  for (int j = 0; j < 2; j++){
    int i = 2*w + j;
    GLOAD_LDS16(A  + (size_t)(row0 + 16*i + srow) * C_ + scol, &As[0][16*i][0]);
    GLOAD_LDS16(Bw + (size_t)(col0 + 16*i + srow) * C_ + scol, &Bs[0][16*i][0]);
  }
  __syncthreads();

  int cur = 0;
  for (int kt = 0; kt < 16; kt++){
    if (kt < 15){
      int k0n = (kt + 1) * 32;
      #pragma unroll
      for (int j = 0; j < 2; j++){
        int i = 2*w + j;
        GLOAD_LDS16(A  + (size_t)(row0 + 16*i + srow) * C_ + k0n + scol, &As[cur^1][16*i][0]);
        GLOAD_LDS16(Bw + (size_t)(col0 + 16*i + srow) * C_ + k0n + scol, &Bs[cur^1][16*i][0]);
      }
    }
    bf16x8 af[4], bfr[4];
    #pragma unroll
    for (int m = 0; m < 4; m++) af[m]  = *(const bf16x8*)&As[cur][wr + m*16 + fr][kq];
    #pragma unroll
    for (int n = 0; n < 4; n++) bfr[n] = *(const bf16x8*)&Bs[cur][wc + n*16 + fr][kq];
    #pragma unroll
    for (int m = 0; m < 4; m++)
      #pragma unroll
      for (int n = 0; n < 4; n++)
        acc[m][n] = __builtin_amdgcn_mfma_f32_16x16x32_bf16(af[m], bfr[n], acc[m][n], 0, 0, 0);
    __syncthreads();
    cur ^= 1;
  }

  int cq = lane & 15, rq = (lane >> 4) * 4;
  #pragma unroll
  for (int n = 0; n < 4; n++){
    int col = col0 + wc + n*16 + cq;
    float bv = bias[col];
    #pragma unroll
    for (int m = 0; m < 4; m++){
      #pragma unroll
      for (int j = 0; j < 4; j++){
        int row = row0 + wr + m*16 + rq + j;
        Cout[(size_t)row * C_ + col] = f2bf(acc[m][n][j] + bv);
      }
    }
  }
}

// ---------------- pooled + gate + merge + LN2 (wave per output row) ----------------
__global__ __launch_bounds__(256) void k_epilogue(
    const ushort_t* __restrict__ red, const ushort_t* __restrict__ pooled,
    const float* __restrict__ gw, const float* __restrict__ gbp,
    const float* __restrict__ g2, const float* __restrict__ b2,
    float* __restrict__ out, float* __restrict__ gateout)
{
  int row  = blockIdx.x * 4 + (threadIdx.x >> 6);   // b*2048 + l
  int lane = threadIdx.x & 63;
  int b = row >> 11, l = row & (LO_ - 1);
  const ushort_t* rr = red + (size_t)row * C_;
  const ushort_t* pp = pooled + (size_t)row * C_;
  float rv[8], pv[8];
  float lp = 0.f;
  #pragma unroll
  for (int i = 0; i < 2; i++){
    int c = i * 256 + lane * 4;
    ushort4 r4 = *(const ushort4*)(rr + c);
    ushort4 p4 = *(const ushort4*)(pp + c);
    float4 w1 = *(const float4*)(gw + c);
    float4 w2 = *(const float4*)(gw + C_ + c);
    float r0 = bf2f(r4.x), r1 = bf2f(r4.y), r2 = bf2f(r4.z), r3 = bf2f(r4.w);
    float q0 = bf2f(p4.x), q1 = bf2f(p4.y), q2 = bf2f(p4.z), q3 = bf2f(p4.w);
    rv[i*4+0] = r0; rv[i*4+1] = r1; rv[i*4+2] = r2; rv[i*4+3] = r3;
    pv[i*4+0] = q0; pv[i*4+1] = q1; pv[i*4+2] = q2; pv[i*4+3] = q3;
    lp += r0*w1.x + r1*w1.y + r2*w1.z + r3*w1.w
        + q0*w2.x + q1*w2.y + q2*w2.z + q3*w2.w;
  }
  lp = waveReduceSum(lp);
  float gate = 0.5f + 0.5f / (1.f + expf(-(lp + gbp[0])));
  float mv[8];
  float s1 = 0.f, s2 = 0.f;
  #pragma unroll
  for (int j = 0; j < 8; j++){
    mv[j] = pv[j] + gate * (rv[j] - pv[j]);
    s1 += mv[j]; s2 += mv[j] * mv[j];
  }
  s1 = waveReduceSum(s1); s2 = waveReduceSum(s2);
  float m = s1 * (1.f / C_);
  float rstd = rsqrtf(s2 * (1.f / C_) - m * m + 1e-5f);
  float* o = out + ((size_t)(b * LM_ + SLOTS + l)) * C_;
  #pragma unroll
  for (int i = 0; i < 2; i++){
    int c = i * 256 + lane * 4;
    float4 gv = *(const float4*)(g2 + c);
    float4 bv = *(const float4*)(b2 + c);
    float4 ov;
    ov.x = (mv[i*4+0] - m) * rstd * gv.x + bv.x;
    ov.y = (mv[i*4+1] - m) * rstd * gv.y + bv.y;
    ov.z = (mv[i*4+2] - m) * rstd * gv.z + bv.z;
    ov.w = (mv[i*4+3] - m) * rstd * gv.w + bv.w;
    *(float4*)(o + c) = ov;
  }
  if (lane == 0) gateout[b * LO_ + l] = gate;
}

extern "C" void kernel_launch(void* const* d_in, const int* in_sizes, int n_in,
                              void* d_out, int out_size, void* d_ws, size_t ws_size,
                              hipStream_t stream)
{
  const float* lat = (const float*)d_in[0];
  const float* g1  = (const float*)d_in[1];
  const float* b1  = (const float*)d_in[2];
  const float* dw  = (const float*)d_in[3];
  const float* db  = (const float*)d_in[4];
  const float* pw  = (const float*)d_in[5];
  const float* pb  = (const float*)d_in[6];
  const float* gw  = (const float*)d_in[7];
  const float* gb  = (const float*)d_in[8];
  const float* cw  = (const float*)d_in[9];
  const float* cb  = (const float*)d_in[10];
  const float* g2  = (const float*)d_in[11];
  const float* b2  = (const float*)d_in[12];

  float* out = (float*)d_out;
  float* gateout = out + (size_t)B_ * LM_ * C_;

  const size_t NHL = (size_t)B_ * LO_ * C_;   // 8388608
  ushort_t* hbuf   = (ushort_t*)d_ws;
  ushort_t* pooled = hbuf + NHL;
  ushort_t* redb   = pooled + NHL;
  ushort_t* pwb    = redb + NHL;
  float*    scores = (float*)(pwb + (size_t)C_ * C_);

  hipLaunchKernelGGL(k_conv,    dim3(B_ * LO_ / 8), dim3(512), 0, stream,
                     lat, g1, b1, dw, db, cw, cb, pw, pwb, hbuf, pooled, scores);
  hipLaunchKernelGGL(k_topk,    dim3(B_), dim3(1024), 0, stream, scores, lat, g2, b2, out);
  hipLaunchKernelGGL(k_gemm,    dim3(4, 128), dim3(256), 0, stream, hbuf, pwb, pb, redb);
  hipLaunchKernelGGL(k_epilogue,dim3(B_ * LO_ / 4), dim3(256), 0, stream, redb, pooled, gw, gb, g2, b2, out, gateout);
}